// Round 1
// baseline (319.476 us; speedup 1.0000x reference)
//
#include <hip/hip_runtime.h>
#include <stdint.h>

// Problem constants (from reference): B,T,X,E,H,L = 4096,32,256,32,512,2
#define B_SZ 4096
#define T_SZ 32
#define X_SZ 256
#define E_SZ 32
#define H_SZ 512
#define BM   64      // batch rows per block
// A-tile LDS row stride: 512 bf16 = 1024B, +16B pad -> conflict-free ds_read_b128
#define AROW 1040

typedef __attribute__((ext_vector_type(8))) short  short8;   // 8 bf16 = 4 VGPR
typedef __attribute__((ext_vector_type(4))) float  floatx4;

__device__ __forceinline__ unsigned short f2bf(float f) {
  unsigned u = __float_as_uint(f);
  u += 0x7fffu + ((u >> 16) & 1u);          // RNE (inputs finite, no NaN care)
  return (unsigned short)(u >> 16);
}
__device__ __forceinline__ unsigned pk2(float a, float b) {
  return (unsigned)f2bf(a) | ((unsigned)f2bf(b) << 16);
}

// ---------------------------------------------------------------------------
// Prep: fp32 weights -> bf16 in MFMA B-fragment order.
// Chunk = (expert, k-chunk of 32): 512 n x 32 k bf16 = 32KB = 2048 x 16B units.
// Unit u in chunk: nb=u>>6, lane=u&63 -> n = nb*16+(lane&15), k = k0..k0+7,
// k0 = kt*32+(lane>>4)*8.  Lane's 8 bf16 (16B) = its mfma_16x16x32 B-fragment.
// W1cat rows 0..31 = masked W1t, rows 32..287 = W1x.
// ---------------------------------------------------------------------------
__global__ __launch_bounds__(256) void prep_kernel(
    const float* __restrict__ W1t, const float* __restrict__ W1x,
    const int* __restrict__ masks, const float* __restrict__ Wh,
    uint4* __restrict__ wcat, uint4* __restrict__ whf) {
  int gid = blockIdx.x * 256 + threadIdx.x;
  const int NU1 = E_SZ * 9 * 2048;          // 589824 units for layer-1 weights
  if (gid < NU1) {
    int c  = gid >> 11;                     // e*9 + kt
    int u  = gid & 2047;
    int e  = c / 9, kt = c - e * 9;
    int nb = u >> 6, l = u & 63;
    int n  = nb * 16 + (l & 15);
    int k0 = kt * 32 + (l >> 4) * 8;
    unsigned r[4];
#pragma unroll
    for (int p = 0; p < 4; ++p) {
      int   k  = k0 + p * 2;
      float v0 = (k < T_SZ)
                     ? W1t[(e * T_SZ + k) * H_SZ + n] * (float)masks[e * T_SZ + k]
                     : W1x[(e * X_SZ + (k - T_SZ)) * H_SZ + n];
      int   k1 = k + 1;
      float v1 = (k1 < T_SZ)
                     ? W1t[(e * T_SZ + k1) * H_SZ + n] * (float)masks[e * T_SZ + k1]
                     : W1x[(e * X_SZ + (k1 - T_SZ)) * H_SZ + n];
      r[p] = pk2(v0, v1);
    }
    wcat[gid] = make_uint4(r[0], r[1], r[2], r[3]);
  } else {
    int g  = gid - NU1;                     // 2*32*16*2048 = 2097152 units
    int c  = g >> 11;                       // (layer*32+e)*16 + kt
    int u  = g & 2047;
    int kt = c & 15, le = c >> 4;
    int nb = u >> 6, l = u & 63;
    int n  = nb * 16 + (l & 15);
    int k0 = kt * 32 + (l >> 4) * 8;
    const float* base = Wh + (size_t)le * H_SZ * H_SZ + n;
    unsigned r[4];
#pragma unroll
    for (int p = 0; p < 4; ++p) {
      float v0 = base[(size_t)(k0 + p * 2) * H_SZ];
      float v1 = base[(size_t)(k0 + p * 2 + 1) * H_SZ];
      r[p] = pk2(v0, v1);
    }
    whf[g] = make_uint4(r[0], r[1], r[2], r[3]);
  }
}

// ---------------------------------------------------------------------------
// Fused MLP: block = (64-row batch tile, expert e). 8 waves; wave w owns
// cols [64w,64w+64). acc 4x4 tiles of mfma_f32_16x16x32_bf16.
// A (activations) in LDS bf16, weights direct-from-global (fragment order).
// ---------------------------------------------------------------------------
__global__ __launch_bounds__(512, 4) void mlp_kernel(
    const float* __restrict__ theta, const float* __restrict__ x,
    const short8* __restrict__ wcat, const short8* __restrict__ whf,
    const float* __restrict__ b1, const float* __restrict__ a1,
    const float* __restrict__ bh, const float* __restrict__ ah,
    const float* __restrict__ Wo, const float* __restrict__ bo,
    float* __restrict__ out) {
  __shared__ __align__(16) char smA[BM * AROW];   // 66560 B (gfx950: 160KB max)
  const int tid = threadIdx.x;
  const int bid = blockIdx.x;
  const int r5  = bid & 31;
  const int e   = (r5 & 7) * 4 + (r5 >> 3);       // same-expert blocks -> same XCD (mod 8)
  const int m0  = (bid >> 5) * BM;
  const int w   = tid >> 6, l = tid & 63, l16 = l & 15, quad = l >> 4;

  // ---- stage A0 = [theta | x] as bf16 (mask folded into prepped W1t) ----
  {
    int r = tid >> 3, c = tid & 7;                // 8 threads per row
    float4 th = *(const float4*)(theta + (size_t)(m0 + r) * T_SZ + c * 4);
    *(uint2*)(smA + r * AROW + c * 8) = make_uint2(pk2(th.x, th.y), pk2(th.z, th.w));
    const float4* xp = (const float4*)(x + (size_t)(m0 + r) * X_SZ + c * 32);
#pragma unroll
    for (int q = 0; q < 4; ++q) {
      float4 a = xp[q * 2], b = xp[q * 2 + 1];
      *(uint4*)(smA + r * AROW + 64 + c * 64 + q * 16) =
          make_uint4(pk2(a.x, a.y), pk2(a.z, a.w), pk2(b.x, b.y), pk2(b.z, b.w));
    }
  }
  __syncthreads();

  floatx4 acc[4][4];

  // GEMM over nkt K-chunks of 32; B double-buffered from global.
  auto gemm = [&](const short8* wbase, int nkt) {
#pragma unroll
    for (int mb = 0; mb < 4; ++mb)
#pragma unroll
      for (int i = 0; i < 4; ++i) acc[mb][i] = (floatx4)(0.f);
    short8 bcur[4], bnxt[4];
    const int boff = w * 256 + l;
#pragma unroll
    for (int i = 0; i < 4; ++i) bcur[i] = wbase[boff + i * 64];
    for (int kt = 0; kt < nkt; ++kt) {
      const short8* wn = wbase + (size_t)(kt + 1 < nkt ? kt + 1 : kt) * 2048;
#pragma unroll
      for (int i = 0; i < 4; ++i) bnxt[i] = wn[boff + i * 64];
      short8 af[4];
#pragma unroll
      for (int mb = 0; mb < 4; ++mb)
        af[mb] = *(const short8*)(smA + (mb * 16 + l16) * AROW + kt * 64 + quad * 16);
#pragma unroll
      for (int mb = 0; mb < 4; ++mb)
#pragma unroll
        for (int i = 0; i < 4; ++i)
          acc[mb][i] = __builtin_amdgcn_mfma_f32_16x16x32_bf16(af[mb], bcur[i],
                                                               acc[mb][i], 0, 0, 0);
#pragma unroll
      for (int i = 0; i < 4; ++i) bcur[i] = bnxt[i];
    }
  };

  // bias + PReLU + bf16 pair-pack (shfl_xor 1) + write back into A buffer
  auto epi_store = [&](const float* bias, const float* slope) {
    float bb[4], aa[4];
#pragma unroll
    for (int i = 0; i < 4; ++i) {
      int col = w * 64 + i * 16 + l16;
      bb[i] = bias[col];
      aa[i] = slope[col];
    }
    __syncthreads();   // everyone done READING A before we overwrite
#pragma unroll
    for (int mb = 0; mb < 4; ++mb) {
#pragma unroll
      for (int i = 0; i < 4; ++i) {
        unsigned dw[4];
#pragma unroll
        for (int r = 0; r < 4; ++r) {
          float v = acc[mb][i][r] + bb[i];
          v = v >= 0.f ? v : aa[i] * v;
          float o  = __shfl_xor(v, 1, 64);
          float lo = (l16 & 1) ? o : v;
          float hi = (l16 & 1) ? v : o;
          dw[r] = pk2(lo, hi);
        }
        int col2  = w * 64 + i * 16 + (l16 & ~1);
        int rbase = (l16 & 1) * 2;                 // even lanes rows 0,1; odd 2,3
#pragma unroll
        for (int rr = 0; rr < 2; ++rr) {
          int row = mb * 16 + quad * 4 + rbase + rr;
          *(unsigned*)(smA + row * AROW + col2 * 2) = dw[rbase + rr];
        }
      }
    }
    __syncthreads();
  };

  // ---- layer 1: K = 288 (9 chunks) ----
  gemm(wcat + (size_t)e * 9 * 2048, 9);
  epi_store(b1 + (size_t)e * H_SZ, a1 + (size_t)e * H_SZ);
  // ---- hidden layer 0: K = 512 (16 chunks) ----
  gemm(whf + (size_t)e * 16 * 2048, 16);
  epi_store(bh + (size_t)e * H_SZ, ah + (size_t)e * H_SZ);
  // ---- hidden layer 1 + fused output dot (fp32, no bf16 rounding) ----
  gemm(whf + (size_t)(E_SZ + e) * 16 * 2048, 16);
  {
    float bb[4], aa[4], wo[4];
#pragma unroll
    for (int i = 0; i < 4; ++i) {
      int col = w * 64 + i * 16 + l16;
      bb[i] = bh[(size_t)(E_SZ + e) * H_SZ + col];
      aa[i] = ah[(size_t)(E_SZ + e) * H_SZ + col];
      wo[i] = Wo[(size_t)e * H_SZ + col];
    }
    float ps[4][4];
#pragma unroll
    for (int mb = 0; mb < 4; ++mb)
#pragma unroll
      for (int r = 0; r < 4; ++r) ps[mb][r] = 0.f;
#pragma unroll
    for (int mb = 0; mb < 4; ++mb)
#pragma unroll
      for (int i = 0; i < 4; ++i)
#pragma unroll
        for (int r = 0; r < 4; ++r) {
          float v = acc[mb][i][r] + bb[i];
          v = v >= 0.f ? v : aa[i] * v;
          ps[mb][r] += v * wo[i];
        }
    // reduce over the 16 lanes of each quad (cols within this wave's slice)
#pragma unroll
    for (int d = 1; d < 16; d <<= 1)
#pragma unroll
      for (int mb = 0; mb < 4; ++mb)
#pragma unroll
        for (int r = 0; r < 4; ++r) ps[mb][r] += __shfl_xor(ps[mb][r], d, 64);
    __syncthreads();                 // done reading A; reuse its storage
    float* scratch = (float*)smA;    // [64 rows][8 waves]
    if (l16 == 0) {
#pragma unroll
      for (int mb = 0; mb < 4; ++mb)
#pragma unroll
        for (int r = 0; r < 4; ++r)
          scratch[(mb * 16 + quad * 4 + r) * 8 + w] = ps[mb][r];
    }
    __syncthreads();
    if (tid < BM) {
      float s = 0.f;
#pragma unroll
      for (int ww = 0; ww < 8; ++ww) s += scratch[tid * 8 + ww];
      out[(size_t)(m0 + tid) * E_SZ + e] = s + bo[e];
    }
  }
}

// ---------------------------------------------------------------------------
extern "C" void kernel_launch(void* const* d_in, const int* in_sizes, int n_in,
                              void* d_out, int out_size, void* d_ws, size_t ws_size,
                              hipStream_t stream) {
  const float* theta = (const float*)d_in[0];
  const float* x     = (const float*)d_in[1];
  const int*   masks = (const int*)d_in[2];
  const float* W1t   = (const float*)d_in[3];
  const float* W1x   = (const float*)d_in[4];
  const float* b1    = (const float*)d_in[5];
  const float* a1    = (const float*)d_in[6];
  const float* Wh    = (const float*)d_in[7];
  const float* bh    = (const float*)d_in[8];
  const float* ah    = (const float*)d_in[9];
  const float* Wo    = (const float*)d_in[10];
  const float* bo    = (const float*)d_in[11];
  float* out = (float*)d_out;

  // ws layout: [0, 9.4MB) layer-1 frags; [9.4MB, 43MB) hidden frags.
  // Requires ws_size >= 43MB (asserted by design; revisit if bench garbage).
  uint4* wcat = (uint4*)d_ws;
  uint4* whf  = (uint4*)((char*)d_ws + (size_t)E_SZ * 9 * 2048 * 16);

  prep_kernel<<<10496, 256, 0, stream>>>(W1t, W1x, masks, Wh, wcat, whf);
  mlp_kernel<<<2048, 512, 0, stream>>>(theta, x, (const short8*)wcat,
                                       (const short8*)whf, b1, a1, bh, ah, Wo, bo,
                                       out);
}